// Round 1
// baseline (234.822 us; speedup 1.0000x reference)
//
#include <hip/hip_runtime.h>
#include <hip/hip_bf16.h>
#include <math.h>

#define H 128
#define EPS 1e-5f
#define INF_BIAS 0.1f

// ---- edge-binning parameters ----
// bin = col >> BIN_SHIFT : 1024 food rows/bin = 256 KB bf16 window (fits L2 easily)
#define BIN_SHIFT 10
#define CAP 24576          // slots per bin; E/nb ~ 20.5k expected, +28 sigma margin
#define NBMAX 64

typedef __attribute__((ext_vector_type(8))) short bf16x8;
typedef __attribute__((ext_vector_type(4))) float f32x4;
typedef __attribute__((ext_vector_type(4))) unsigned int u32x4;

// ---- bf16 helpers (RNE) ----
__device__ inline unsigned short f2bf_rne(float f) {
    unsigned u = __float_as_uint(f);
    u += 0x7fffu + ((u >> 16) & 1u);
    return (unsigned short)(u >> 16);
}
__device__ inline float bf2f(unsigned short h) {
    return __uint_as_float(((unsigned)h) << 16);
}
__device__ inline unsigned pack2(float a, float b) {
    return (unsigned)f2bf_rne(a) | ((unsigned)f2bf_rne(b) << 16);
}
__device__ inline float2 unpack2(unsigned v) {
    float2 r;
    r.x = __uint_as_float(v << 16);
    r.y = __uint_as_float(v & 0xffff0000u);
    return r;
}

// ---------------------------------------------------------------------------
// prep: BN-prescaled bf16 W in MFMA A-fragment order (unchanged math) +
// zeroing of the 64 bin cursors (runs before bin_scatter in stream order).
// ---------------------------------------------------------------------------
__global__ void prep_kernel(
    const float* __restrict__ W1, const float* __restrict__ b1,
    const float* __restrict__ gamma, const float* __restrict__ beta,
    const float* __restrict__ rm, const float* __restrict__ rv,
    unsigned short* __restrict__ Wswz_u, unsigned short* __restrict__ Wswz_f,
    float* __restrict__ d_user, int* __restrict__ binCursor, int useBinned)
{
    const int f    = blockIdx.x;          // 0..31
    const int half = f >> 4, nt = (f >> 2) & 3, kt = f & 3;
    const int t    = threadIdx.x;         // 0..63
    const int c    = t & 15, q = t >> 4;

    if (useBinned && f == 0) binCursor[t] = 0;   // 64 cursors, one per thread

    const int j  = half * 64 + (c >> 2) * 16 + nt * 4 + (c & 3);
    const float a = gamma[j] * rsqrtf(rv[j] + EPS);
    const int k0 = kt * 32 + q * 8;

    unsigned short wu[8], wf[8];
    #pragma unroll
    for (int i = 0; i < 8; ++i) {
        wu[i] = f2bf_rne(a * W1[(size_t)j * (2 * H) + k0 + i]);
        wf[i] = f2bf_rne(a * W1[(size_t)j * (2 * H) + H + k0 + i]);
    }
    const size_t dst = (size_t)f * 512 + (size_t)t * 8;   // ushort units
    #pragma unroll
    for (int i = 0; i < 8; ++i) { Wswz_u[dst + i] = wu[i]; Wswz_f[dst + i] = wf[i]; }

    if (kt == 0 && q == 0) d_user[j] = a * (b1[j] - rm[j]) + beta[j];
}

// ---------------------------------------------------------------------------
// proj_mfma v8 (unchanged): persistent waves + register double-buffered Z
// prefetch. Bit-identical per-tile math to previous round.
// ---------------------------------------------------------------------------
__global__ __launch_bounds__(256, 2) void proj_mfma(
    const float* __restrict__ z_user, const float* __restrict__ z_food,
    const unsigned short* __restrict__ Wswz_u, const unsigned short* __restrict__ Wswz_f,
    const float* __restrict__ d_user,
    unsigned short* __restrict__ U, unsigned short* __restrict__ F,
    int n_users, int n_foods, int GU, int GB)
{
    const bool userMode = (blockIdx.x < (unsigned)GU);
    const float* Z;
    const unsigned short* Wsrc;
    unsigned short* Out;
    int n, blk0, nblk;
    if (userMode) { Z = z_user; Wsrc = Wswz_u; Out = U; n = n_users; blk0 = blockIdx.x;      nblk = GU; }
    else          { Z = z_food; Wsrc = Wswz_f; Out = F; n = n_foods; blk0 = blockIdx.x - GU; nblk = GB - GU; }
    const int tiles = n >> 4;               // n divisible by 16

    const int wave = threadIdx.x >> 6;
    const int lane = threadIdx.x & 63;
    const int c = lane & 15;                // row within tile
    const int q = lane >> 4;                // k-group / 16-col subgroup
    const int wg   = blk0 * 4 + wave;       // global wave id within mode
    const int half = wg & 1;                // 64-col half
    const int pair = wg >> 1;               // tile-pair id
    const int stride = nblk * 2;            // tile stride between iterations

    bf16x8 wf[4][4];
    #pragma unroll
    for (int nt = 0; nt < 4; ++nt)
        #pragma unroll
        for (int kt = 0; kt < 4; ++kt)
            wf[nt][kt] = *(const bf16x8*)(Wsrc + (size_t)(half * 16 + nt * 4 + kt) * 512 + lane * 8);

    f32x4 dvec[4];
    #pragma unroll
    for (int nt = 0; nt < 4; ++nt) {
        if (userMode) {
            float4 d = *(const float4*)(d_user + half * 64 + q * 16 + nt * 4);
            dvec[nt] = (f32x4){d.x, d.y, d.z, d.w};
        } else {
            dvec[nt] = (f32x4){0.f, 0.f, 0.f, 0.f};
        }
    }

    auto loadZ = [&](int t, float4 zb[8]) {
        const float* zrow = Z + (size_t)(min(t, tiles - 1) * 16 + c) * H;
        #pragma unroll
        for (int kt = 0; kt < 4; ++kt) {
            const int k0 = kt * 32 + q * 8;
            zb[2 * kt + 0] = ((const float4*)(zrow + k0))[0];
            zb[2 * kt + 1] = ((const float4*)(zrow + k0))[1];
        }
    };

    auto computeStore = [&](int t, const float4 zb[8]) {
        f32x4 acc[4];
        #pragma unroll
        for (int nt = 0; nt < 4; ++nt) acc[nt] = dvec[nt];

        #pragma unroll
        for (int kt = 0; kt < 4; ++kt) {
            float4 za = zb[2 * kt + 0];
            float4 zv = zb[2 * kt + 1];
            bf16x8 zhi, zlo;
            {
                float v[8] = {za.x, za.y, za.z, za.w, zv.x, zv.y, zv.z, zv.w};
                #pragma unroll
                for (int i = 0; i < 8; ++i) {
                    unsigned short hi = f2bf_rne(v[i]);
                    unsigned short lo = f2bf_rne(v[i] - bf2f(hi));
                    zhi[i] = (short)hi; zlo[i] = (short)lo;
                }
            }
            #pragma unroll
            for (int nt = 0; nt < 4; ++nt) {
                acc[nt] = __builtin_amdgcn_mfma_f32_16x16x32_bf16(wf[nt][kt], zhi, acc[nt], 0, 0, 0);
                acc[nt] = __builtin_amdgcn_mfma_f32_16x16x32_bf16(wf[nt][kt], zlo, acc[nt], 0, 0, 0);
            }
        }

        if (t < tiles) {
            const int r = t * 16 + c;
            unsigned short* obase = Out + (size_t)r * H + half * 64 + q * 16;
            uint4 p0, p1;
            p0.x = pack2(acc[0][0], acc[0][1]); p0.y = pack2(acc[0][2], acc[0][3]);
            p0.z = pack2(acc[1][0], acc[1][1]); p0.w = pack2(acc[1][2], acc[1][3]);
            p1.x = pack2(acc[2][0], acc[2][1]); p1.y = pack2(acc[2][2], acc[2][3]);
            p1.z = pack2(acc[3][0], acc[3][1]); p1.w = pack2(acc[3][2], acc[3][3]);
            *(uint4*)(obase)     = p0;
            *(uint4*)(obase + 8) = p1;
        }
    };

    int nIt = (tiles + stride - 1) / stride;
    nIt = (nIt + 1) & ~1;                   // even, for 2x unrolled pipeline

    float4 zb0[8], zb1[8];
    int t = pair;
    loadZ(t, zb0);
    for (int it = 0; it < nIt; it += 2) {
        loadZ(t + stride, zb1);
        computeStore(t, zb0);
        if (it + 2 < nIt) loadZ(t + 2 * stride, zb0);
        computeStore(t + stride, zb1);
        t += 2 * stride;
    }
}

// ---------------------------------------------------------------------------
// bin_scatter: single-pass binning of edges by food bin (col >> BIN_SHIFT).
// Per block: LDS histogram -> one global atomicAdd per non-empty bin to
// reserve a contiguous range -> LDS-cursor scatter of (row, col, e).
// Output order within a bin is nondeterministic but per-edge results are
// order-independent, so final out[] is deterministic.
// ---------------------------------------------------------------------------
__global__ __launch_bounds__(256) void bin_scatter(
    const int* __restrict__ row, const int* __restrict__ col, int E,
    int* __restrict__ binCursor,
    int* __restrict__ br, int* __restrict__ bc, int* __restrict__ be)
{
    __shared__ int h[NBMAX];
    __shared__ int cur[NBMAX];
    const int t = threadIdx.x;
    const int chunk = (E + gridDim.x - 1) / gridDim.x;
    const int e0 = blockIdx.x * chunk;
    const int e1 = min(E, e0 + chunk);

    if (t < NBMAX) h[t] = 0;
    __syncthreads();
    for (int e = e0 + t; e < e1; e += 256)
        atomicAdd(&h[col[e] >> BIN_SHIFT], 1);
    __syncthreads();
    if (t < NBMAX) {
        const int c_ = h[t];
        const int old = c_ ? atomicAdd(&binCursor[t], c_) : 0;
        cur[t] = t * CAP + old;
    }
    __syncthreads();
    for (int e = e0 + t; e < e1; e += 256) {
        const int c = col[e];
        const int b = c >> BIN_SHIFT;
        const int pos = atomicAdd(&cur[b], 1);
        if (pos < (b + 1) * CAP) {         // capacity guard (never expected)
            br[pos] = row[e];
            bc[pos] = c;
            be[pos] = e;
        }
    }
}

// ---------------------------------------------------------------------------
// edge_binned: same per-edge math as edge_kernel, but edges come from the
// bin-ordered arrays. Blocks take contiguous slot chunks in launch order ->
// sliding window over bins -> hot 256 KB F-window stays L2-resident.
// U-side gathers are non-temporal so the streaming U traffic doesn't evict
// the F window.
// ---------------------------------------------------------------------------
__global__ __launch_bounds__(256) void edge_binned(
    const unsigned short* __restrict__ U, const unsigned short* __restrict__ F,
    const int* __restrict__ br, const int* __restrict__ bc, const int* __restrict__ be,
    const int* __restrict__ binCursor,
    const float* __restrict__ W2, const float* __restrict__ b2,
    float* __restrict__ out)
{
    const int lane  = threadIdx.x & 15;
    const int g     = (blockIdx.x * blockDim.x + threadIdx.x) >> 4;
    const int slot0 = g * 4;                 // 4 consecutive slots, same bin (CAP%4==0)
    const int bin   = slot0 / CAP;
    const int base  = bin * CAP;
    int cnt = binCursor[bin];
    cnt = min(cnt, CAP);
    const int idx0 = slot0 - base;
    if (idx0 >= cnt) return;                 // whole group past this bin's fill

    const float4 w2a = ((const float4*)W2)[2 * lane];
    const float4 w2b = ((const float4*)W2)[2 * lane + 1];
    const float bias = b2[0] + INF_BIAS;

    bool act[4];
    int iu[4], ifo[4];
    #pragma unroll
    for (int i = 0; i < 4; ++i) {
        act[i] = (idx0 + i) < cnt;
        const int s = act[i] ? (slot0 + i) : slot0;
        iu[i]  = br[s];
        ifo[i] = bc[s];
    }
    u32x4 uv[4];
    uint4 fv[4];
    #pragma unroll
    for (int i = 0; i < 4; ++i) {
        uv[i] = __builtin_nontemporal_load(((const u32x4*)(U + (size_t)iu[i] * H)) + lane);
        fv[i] = ((const uint4*)(F + (size_t)ifo[i] * H))[lane];
    }
    #pragma unroll
    for (int i = 0; i < 4; ++i) {
        float2 u0 = unpack2(uv[i][0]), f0 = unpack2(fv[i].x);
        float2 u1 = unpack2(uv[i][1]), f1 = unpack2(fv[i].y);
        float2 u2 = unpack2(uv[i][2]), f2 = unpack2(fv[i].z);
        float2 u3 = unpack2(uv[i][3]), f3 = unpack2(fv[i].w);

        float s =
            w2a.x * fmaxf(u0.x + f0.x, 0.0f) +
            w2a.y * fmaxf(u0.y + f0.y, 0.0f) +
            w2a.z * fmaxf(u1.x + f1.x, 0.0f) +
            w2a.w * fmaxf(u1.y + f1.y, 0.0f) +
            w2b.x * fmaxf(u2.x + f2.x, 0.0f) +
            w2b.y * fmaxf(u2.y + f2.y, 0.0f) +
            w2b.z * fmaxf(u3.x + f3.x, 0.0f) +
            w2b.w * fmaxf(u3.y + f3.y, 0.0f);

        s += __shfl_xor(s, 8, 16);
        s += __shfl_xor(s, 4, 16);
        s += __shfl_xor(s, 2, 16);
        s += __shfl_xor(s, 1, 16);

        if (lane == 0 && act[i]) {
            const float x = s + bias;
            out[be[slot0 + i]] = 1.0f / (1.0f + __expf(-x));
        }
    }
}

// ---------------------------------------------------------------------------
// edge kernel v2 (fallback path if workspace too small): unchanged.
// ---------------------------------------------------------------------------
#define EUN 4
__global__ __launch_bounds__(256) void edge_kernel(
    const unsigned short* __restrict__ U, const unsigned short* __restrict__ F,
    const int* __restrict__ row, const int* __restrict__ col,
    const float* __restrict__ W2, const float* __restrict__ b2,
    float* __restrict__ out, int E)
{
    const int lane = threadIdx.x & 15;
    const int g  = (blockIdx.x * blockDim.x + threadIdx.x) >> 4;
    const int nG = (gridDim.x * blockDim.x) >> 4;

    const float4 w2a = ((const float4*)W2)[2 * lane];
    const float4 w2b = ((const float4*)W2)[2 * lane + 1];
    const float bias = b2[0] + INF_BIAS;

    for (int e0 = g; e0 < E; e0 += EUN * nG) {
        int iu[EUN], ifo[EUN];
        #pragma unroll
        for (int i = 0; i < EUN; ++i) {
            int e  = e0 + i * nG;
            int ec = (e < E) ? e : e0;
            iu[i]  = row[ec];
            ifo[i] = col[ec];
        }
        uint4 uv[EUN], fv[EUN];
        #pragma unroll
        for (int i = 0; i < EUN; ++i) {
            uv[i] = ((const uint4*)(U + (size_t)iu[i]  * H))[lane];
            fv[i] = ((const uint4*)(F + (size_t)ifo[i] * H))[lane];
        }
        #pragma unroll
        for (int i = 0; i < EUN; ++i) {
            float2 u0 = unpack2(uv[i].x), f0 = unpack2(fv[i].x);
            float2 u1 = unpack2(uv[i].y), f1 = unpack2(fv[i].y);
            float2 u2 = unpack2(uv[i].z), f2 = unpack2(fv[i].z);
            float2 u3 = unpack2(uv[i].w), f3 = unpack2(fv[i].w);

            float s =
                w2a.x * fmaxf(u0.x + f0.x, 0.0f) +
                w2a.y * fmaxf(u0.y + f0.y, 0.0f) +
                w2a.z * fmaxf(u1.x + f1.x, 0.0f) +
                w2a.w * fmaxf(u1.y + f1.y, 0.0f) +
                w2b.x * fmaxf(u2.x + f2.x, 0.0f) +
                w2b.y * fmaxf(u2.y + f2.y, 0.0f) +
                w2b.z * fmaxf(u3.x + f3.x, 0.0f) +
                w2b.w * fmaxf(u3.y + f3.y, 0.0f);

            s += __shfl_xor(s, 8, 16);
            s += __shfl_xor(s, 4, 16);
            s += __shfl_xor(s, 2, 16);
            s += __shfl_xor(s, 1, 16);

            const int e = e0 + i * nG;
            if (lane == 0 && e < E) {
                float x = s + bias;
                out[e] = 1.0f / (1.0f + __expf(-x));
            }
        }
    }
}

extern "C" void kernel_launch(void* const* d_in, const int* in_sizes, int n_in,
                              void* d_out, int out_size, void* d_ws, size_t ws_size,
                              hipStream_t stream) {
    const float* z_user = (const float*)d_in[0];
    const float* z_food = (const float*)d_in[1];
    const int*   row    = (const int*)d_in[2];
    const int*   col    = (const int*)d_in[3];
    const float* W1     = (const float*)d_in[4];
    const float* b1     = (const float*)d_in[5];
    const float* gamma  = (const float*)d_in[6];
    const float* beta   = (const float*)d_in[7];
    const float* rm     = (const float*)d_in[8];
    const float* rv     = (const float*)d_in[9];
    const float* W2     = (const float*)d_in[10];
    const float* b2     = (const float*)d_in[11];
    float* out = (float*)d_out;

    const int n_users = in_sizes[0] / H;
    const int n_foods = in_sizes[1] / H;
    const int E       = in_sizes[2];

    // workspace layout
    unsigned short* U      = (unsigned short*)d_ws;        // n_users*128 bf16
    unsigned short* F      = U + (size_t)n_users * H;      // n_foods*128 bf16
    unsigned short* Wswz_u = F + (size_t)n_foods * H;      // 128*128 bf16, frag order
    unsigned short* Wswz_f = Wswz_u + H * H;               // 128*128 bf16, frag order
    float*          d_usr  = (float*)(Wswz_f + H * H);     // 128 f32
    int*            binCursor = (int*)(d_usr + H);         // 64 ints
    int*            br     = binCursor + NBMAX;            // binned arrays follow

    const int nb = (n_foods + (1 << BIN_SHIFT) - 1) >> BIN_SHIFT;
    int* bc = br + (size_t)nb * CAP;
    int* be = bc + (size_t)nb * CAP;
    const size_t need = (size_t)((char*)(be + (size_t)nb * CAP) - (char*)d_ws);
    const bool binned = (nb >= 1 && nb <= NBMAX && ws_size >= need);

    prep_kernel<<<32, 64, 0, stream>>>(W1, b1, gamma, beta, rm, rv,
                                       Wswz_u, Wswz_f, d_usr,
                                       binCursor, binned ? 1 : 0);

    if (binned)
        bin_scatter<<<512, 256, 0, stream>>>(row, col, E, binCursor, br, bc, be);

    // persistent: ~2 blocks/CU, 2:1 user:food split matches row ratio
    const int GU = 342, GB = 512;
    proj_mfma<<<GB, 256, 0, stream>>>(z_user, z_food, Wswz_u, Wswz_f, d_usr,
                                      U, F, n_users, n_foods, GU, GB);

    if (binned) {
        edge_binned<<<nb * (CAP / 64), 256, 0, stream>>>(U, F, br, bc, be, binCursor,
                                                         W2, b2, out);
    } else {
        edge_kernel<<<8192, 256, 0, stream>>>(U, F, row, col, W2, b2, out, E);
    }
}

// Round 2
// 228.039 us; speedup vs baseline: 1.0297x; 1.0297x over previous
//
#include <hip/hip_runtime.h>
#include <hip/hip_bf16.h>
#include <math.h>

#define H 128
#define EPS 1e-5f
#define INF_BIAS 0.1f

// ---- edge-binning parameters ----
// bin = col >> BIN_SHIFT : 1024 food rows/bin = 256 KB bf16 window (L2-resident)
#define BIN_SHIFT 10
#define CAP 24576          // slots per bin; E/nb ~ 20.4k expected, +29 sigma margin
#define NBMAX 64

typedef __attribute__((ext_vector_type(8))) short bf16x8;
typedef __attribute__((ext_vector_type(4))) float f32x4;
typedef __attribute__((ext_vector_type(4))) unsigned int u32x4;

// ---- bf16 helpers (RNE) ----
__device__ inline unsigned short f2bf_rne(float f) {
    unsigned u = __float_as_uint(f);
    u += 0x7fffu + ((u >> 16) & 1u);
    return (unsigned short)(u >> 16);
}
__device__ inline float bf2f(unsigned short h) {
    return __uint_as_float(((unsigned)h) << 16);
}
__device__ inline unsigned pack2(float a, float b) {
    return (unsigned)f2bf_rne(a) | ((unsigned)f2bf_rne(b) << 16);
}
__device__ inline float2 unpack2(unsigned v) {
    float2 r;
    r.x = __uint_as_float(v << 16);
    r.y = __uint_as_float(v & 0xffff0000u);
    return r;
}

// ---------------------------------------------------------------------------
// prep: BN-prescaled bf16 W in MFMA A-fragment order (unchanged math) +
// zeroing of the 64 bin cursors (runs before bin_scatter in stream order).
// ---------------------------------------------------------------------------
__global__ void prep_kernel(
    const float* __restrict__ W1, const float* __restrict__ b1,
    const float* __restrict__ gamma, const float* __restrict__ beta,
    const float* __restrict__ rm, const float* __restrict__ rv,
    unsigned short* __restrict__ Wswz_u, unsigned short* __restrict__ Wswz_f,
    float* __restrict__ d_user, int* __restrict__ binCursor, int useBinned)
{
    const int f    = blockIdx.x;          // 0..31
    const int half = f >> 4, nt = (f >> 2) & 3, kt = f & 3;
    const int t    = threadIdx.x;         // 0..63
    const int c    = t & 15, q = t >> 4;

    if (useBinned && f == 0) binCursor[t] = 0;   // 64 cursors, one per thread

    const int j  = half * 64 + (c >> 2) * 16 + nt * 4 + (c & 3);
    const float a = gamma[j] * rsqrtf(rv[j] + EPS);
    const int k0 = kt * 32 + q * 8;

    unsigned short wu[8], wf[8];
    #pragma unroll
    for (int i = 0; i < 8; ++i) {
        wu[i] = f2bf_rne(a * W1[(size_t)j * (2 * H) + k0 + i]);
        wf[i] = f2bf_rne(a * W1[(size_t)j * (2 * H) + H + k0 + i]);
    }
    const size_t dst = (size_t)f * 512 + (size_t)t * 8;   // ushort units
    #pragma unroll
    for (int i = 0; i < 8; ++i) { Wswz_u[dst + i] = wu[i]; Wswz_f[dst + i] = wf[i]; }

    if (kt == 0 && q == 0) d_user[j] = a * (b1[j] - rm[j]) + beta[j];
}

// ---------------------------------------------------------------------------
// proj_mfma v8 (unchanged): persistent waves + register double-buffered Z
// prefetch. Bit-identical per-tile math to previous rounds.
// ---------------------------------------------------------------------------
__global__ __launch_bounds__(256, 2) void proj_mfma(
    const float* __restrict__ z_user, const float* __restrict__ z_food,
    const unsigned short* __restrict__ Wswz_u, const unsigned short* __restrict__ Wswz_f,
    const float* __restrict__ d_user,
    unsigned short* __restrict__ U, unsigned short* __restrict__ F,
    int n_users, int n_foods, int GU, int GB)
{
    const bool userMode = (blockIdx.x < (unsigned)GU);
    const float* Z;
    const unsigned short* Wsrc;
    unsigned short* Out;
    int n, blk0, nblk;
    if (userMode) { Z = z_user; Wsrc = Wswz_u; Out = U; n = n_users; blk0 = blockIdx.x;      nblk = GU; }
    else          { Z = z_food; Wsrc = Wswz_f; Out = F; n = n_foods; blk0 = blockIdx.x - GU; nblk = GB - GU; }
    const int tiles = n >> 4;               // n divisible by 16

    const int wave = threadIdx.x >> 6;
    const int lane = threadIdx.x & 63;
    const int c = lane & 15;                // row within tile
    const int q = lane >> 4;                // k-group / 16-col subgroup
    const int wg   = blk0 * 4 + wave;       // global wave id within mode
    const int half = wg & 1;                // 64-col half
    const int pair = wg >> 1;               // tile-pair id
    const int stride = nblk * 2;            // tile stride between iterations

    bf16x8 wf[4][4];
    #pragma unroll
    for (int nt = 0; nt < 4; ++nt)
        #pragma unroll
        for (int kt = 0; kt < 4; ++kt)
            wf[nt][kt] = *(const bf16x8*)(Wsrc + (size_t)(half * 16 + nt * 4 + kt) * 512 + lane * 8);

    f32x4 dvec[4];
    #pragma unroll
    for (int nt = 0; nt < 4; ++nt) {
        if (userMode) {
            float4 d = *(const float4*)(d_user + half * 64 + q * 16 + nt * 4);
            dvec[nt] = (f32x4){d.x, d.y, d.z, d.w};
        } else {
            dvec[nt] = (f32x4){0.f, 0.f, 0.f, 0.f};
        }
    }

    auto loadZ = [&](int t, float4 zb[8]) {
        const float* zrow = Z + (size_t)(min(t, tiles - 1) * 16 + c) * H;
        #pragma unroll
        for (int kt = 0; kt < 4; ++kt) {
            const int k0 = kt * 32 + q * 8;
            zb[2 * kt + 0] = ((const float4*)(zrow + k0))[0];
            zb[2 * kt + 1] = ((const float4*)(zrow + k0))[1];
        }
    };

    auto computeStore = [&](int t, const float4 zb[8]) {
        f32x4 acc[4];
        #pragma unroll
        for (int nt = 0; nt < 4; ++nt) acc[nt] = dvec[nt];

        #pragma unroll
        for (int kt = 0; kt < 4; ++kt) {
            float4 za = zb[2 * kt + 0];
            float4 zv = zb[2 * kt + 1];
            bf16x8 zhi, zlo;
            {
                float v[8] = {za.x, za.y, za.z, za.w, zv.x, zv.y, zv.z, zv.w};
                #pragma unroll
                for (int i = 0; i < 8; ++i) {
                    unsigned short hi = f2bf_rne(v[i]);
                    unsigned short lo = f2bf_rne(v[i] - bf2f(hi));
                    zhi[i] = (short)hi; zlo[i] = (short)lo;
                }
            }
            #pragma unroll
            for (int nt = 0; nt < 4; ++nt) {
                acc[nt] = __builtin_amdgcn_mfma_f32_16x16x32_bf16(wf[nt][kt], zhi, acc[nt], 0, 0, 0);
                acc[nt] = __builtin_amdgcn_mfma_f32_16x16x32_bf16(wf[nt][kt], zlo, acc[nt], 0, 0, 0);
            }
        }

        if (t < tiles) {
            const int r = t * 16 + c;
            unsigned short* obase = Out + (size_t)r * H + half * 64 + q * 16;
            uint4 p0, p1;
            p0.x = pack2(acc[0][0], acc[0][1]); p0.y = pack2(acc[0][2], acc[0][3]);
            p0.z = pack2(acc[1][0], acc[1][1]); p0.w = pack2(acc[1][2], acc[1][3]);
            p1.x = pack2(acc[2][0], acc[2][1]); p1.y = pack2(acc[2][2], acc[2][3]);
            p1.z = pack2(acc[3][0], acc[3][1]); p1.w = pack2(acc[3][2], acc[3][3]);
            *(uint4*)(obase)     = p0;
            *(uint4*)(obase + 8) = p1;
        }
    };

    int nIt = (tiles + stride - 1) / stride;
    nIt = (nIt + 1) & ~1;                   // even, for 2x unrolled pipeline

    float4 zb0[8], zb1[8];
    int t = pair;
    loadZ(t, zb0);
    for (int it = 0; it < nIt; it += 2) {
        loadZ(t + stride, zb1);
        computeStore(t, zb0);
        if (it + 2 < nIt) loadZ(t + 2 * stride, zb0);
        computeStore(t + stride, zb1);
        t += 2 * stride;
    }
}

// ---------------------------------------------------------------------------
// bin_scatter v2: bins edges by food bin (col >> BIN_SHIFT).
// Scattered traffic minimized: ONE packed int per edge ((row<<10)|col_off)
// to the bin region; slotOf[e] (needed by unscatter) is written COALESCED.
// ---------------------------------------------------------------------------
__global__ __launch_bounds__(256) void bin_scatter(
    const int* __restrict__ row, const int* __restrict__ col, int E,
    int* __restrict__ binCursor,
    int* __restrict__ bpk, int* __restrict__ slotOf)
{
    __shared__ int h[NBMAX];
    __shared__ int cur[NBMAX];
    const int t = threadIdx.x;
    const int chunk = (E + gridDim.x - 1) / gridDim.x;
    const int e0 = blockIdx.x * chunk;
    const int e1 = min(E, e0 + chunk);

    if (t < NBMAX) h[t] = 0;
    __syncthreads();
    for (int e = e0 + t; e < e1; e += 256)
        atomicAdd(&h[col[e] >> BIN_SHIFT], 1);
    __syncthreads();
    if (t < NBMAX) {
        const int c_ = h[t];
        const int old = c_ ? atomicAdd(&binCursor[t], c_) : 0;
        cur[t] = t * CAP + old;
    }
    __syncthreads();
    for (int e = e0 + t; e < e1; e += 256) {
        const int c = col[e];
        const int b = c >> BIN_SHIFT;
        int pos = atomicAdd(&cur[b], 1);
        pos = min(pos, (b + 1) * CAP - 1);   // overflow clamp (statistically impossible)
        bpk[pos]   = (row[e] << BIN_SHIFT) | (c & ((1 << BIN_SHIFT) - 1));
        slotOf[e]  = pos;                    // coalesced in e
    }
}

// ---------------------------------------------------------------------------
// edge_binned v2: edges in bin order -> F gathers hit the L2-resident window.
// U gathers non-temporal (no L2-timescale reuse; don't evict the F window).
// Results written CONTIGUOUSLY to res[slot] (float4 per 4-edge group).
// Per-edge arithmetic bit-identical to the original edge kernel.
// ---------------------------------------------------------------------------
__global__ __launch_bounds__(256) void edge_binned(
    const unsigned short* __restrict__ U, const unsigned short* __restrict__ F,
    const int* __restrict__ bpk, const int* __restrict__ binCursor,
    const float* __restrict__ W2, const float* __restrict__ b2,
    float* __restrict__ res)
{
    const int lane  = threadIdx.x & 15;
    const int g     = (blockIdx.x * blockDim.x + threadIdx.x) >> 4;
    const int slot0 = g * 4;                 // 4 consecutive slots, same bin (CAP%4==0)
    const int bin   = slot0 / CAP;
    const int cnt   = min(binCursor[bin], CAP);
    const int idx0  = slot0 - bin * CAP;
    if (idx0 >= cnt) return;                 // whole group past this bin's fill

    const float4 w2a = ((const float4*)W2)[2 * lane];
    const float4 w2b = ((const float4*)W2)[2 * lane + 1];
    const float bias = b2[0] + INF_BIAS;
    const int   fbase = bin << BIN_SHIFT;

    int iu[4], ifo[4];
    #pragma unroll
    for (int i = 0; i < 4; ++i) {
        const int s = (idx0 + i < cnt) ? (slot0 + i) : slot0;
        const int v = bpk[s];
        iu[i]  = v >> BIN_SHIFT;
        ifo[i] = fbase + (v & ((1 << BIN_SHIFT) - 1));
    }
    u32x4 uv[4];
    uint4 fv[4];
    #pragma unroll
    for (int i = 0; i < 4; ++i) {
        uv[i] = __builtin_nontemporal_load(((const u32x4*)(U + (size_t)iu[i] * H)) + lane);
        fv[i] = ((const uint4*)(F + (size_t)ifo[i] * H))[lane];
    }
    float r[4];
    #pragma unroll
    for (int i = 0; i < 4; ++i) {
        float2 u0 = unpack2(uv[i][0]), f0 = unpack2(fv[i].x);
        float2 u1 = unpack2(uv[i][1]), f1 = unpack2(fv[i].y);
        float2 u2 = unpack2(uv[i][2]), f2 = unpack2(fv[i].z);
        float2 u3 = unpack2(uv[i][3]), f3 = unpack2(fv[i].w);

        float s =
            w2a.x * fmaxf(u0.x + f0.x, 0.0f) +
            w2a.y * fmaxf(u0.y + f0.y, 0.0f) +
            w2a.z * fmaxf(u1.x + f1.x, 0.0f) +
            w2a.w * fmaxf(u1.y + f1.y, 0.0f) +
            w2b.x * fmaxf(u2.x + f2.x, 0.0f) +
            w2b.y * fmaxf(u2.y + f2.y, 0.0f) +
            w2b.z * fmaxf(u3.x + f3.x, 0.0f) +
            w2b.w * fmaxf(u3.y + f3.y, 0.0f);

        s += __shfl_xor(s, 8, 16);
        s += __shfl_xor(s, 4, 16);
        s += __shfl_xor(s, 2, 16);
        s += __shfl_xor(s, 1, 16);

        const float x = s + bias;
        r[i] = 1.0f / (1.0f + __expf(-x));
    }
    if (lane == 0) {                         // contiguous 16B per group, 64B per wave
        float4 o; o.x = r[0]; o.y = r[1]; o.z = r[2]; o.w = r[3];
        *(float4*)(res + slot0) = o;
    }
}

// ---------------------------------------------------------------------------
// unscatter: out[e] = res[slotOf[e]]. Coalesced int4/float4 in e; the res
// gather is confined to the 4.8 MB res array (cache-resident).
// ---------------------------------------------------------------------------
__global__ __launch_bounds__(256) void unscatter(
    const float* __restrict__ res, const int* __restrict__ slotOf,
    float* __restrict__ out, int E)
{
    const int tid = blockIdx.x * blockDim.x + threadIdx.x;
    const int nT  = gridDim.x * blockDim.x;
    const int n4  = E >> 2;
    for (int i = tid; i < n4; i += nT) {
        int4 s = ((const int4*)slotOf)[i];
        float4 o;
        o.x = res[s.x]; o.y = res[s.y]; o.z = res[s.z]; o.w = res[s.w];
        ((float4*)out)[i] = o;
    }
    for (int e = (n4 << 2) + tid; e < E; e += nT)
        out[e] = res[slotOf[e]];
}

// ---------------------------------------------------------------------------
// edge kernel v2 (fallback path if workspace too small): unchanged.
// ---------------------------------------------------------------------------
#define EUN 4
__global__ __launch_bounds__(256) void edge_kernel(
    const unsigned short* __restrict__ U, const unsigned short* __restrict__ F,
    const int* __restrict__ row, const int* __restrict__ col,
    const float* __restrict__ W2, const float* __restrict__ b2,
    float* __restrict__ out, int E)
{
    const int lane = threadIdx.x & 15;
    const int g  = (blockIdx.x * blockDim.x + threadIdx.x) >> 4;
    const int nG = (gridDim.x * blockDim.x) >> 4;

    const float4 w2a = ((const float4*)W2)[2 * lane];
    const float4 w2b = ((const float4*)W2)[2 * lane + 1];
    const float bias = b2[0] + INF_BIAS;

    for (int e0 = g; e0 < E; e0 += EUN * nG) {
        int iu[EUN], ifo[EUN];
        #pragma unroll
        for (int i = 0; i < EUN; ++i) {
            int e  = e0 + i * nG;
            int ec = (e < E) ? e : e0;
            iu[i]  = row[ec];
            ifo[i] = col[ec];
        }
        uint4 uv[EUN], fv[EUN];
        #pragma unroll
        for (int i = 0; i < EUN; ++i) {
            uv[i] = ((const uint4*)(U + (size_t)iu[i]  * H))[lane];
            fv[i] = ((const uint4*)(F + (size_t)ifo[i] * H))[lane];
        }
        #pragma unroll
        for (int i = 0; i < EUN; ++i) {
            float2 u0 = unpack2(uv[i].x), f0 = unpack2(fv[i].x);
            float2 u1 = unpack2(uv[i].y), f1 = unpack2(fv[i].y);
            float2 u2 = unpack2(uv[i].z), f2 = unpack2(fv[i].z);
            float2 u3 = unpack2(uv[i].w), f3 = unpack2(fv[i].w);

            float s =
                w2a.x * fmaxf(u0.x + f0.x, 0.0f) +
                w2a.y * fmaxf(u0.y + f0.y, 0.0f) +
                w2a.z * fmaxf(u1.x + f1.x, 0.0f) +
                w2a.w * fmaxf(u1.y + f1.y, 0.0f) +
                w2b.x * fmaxf(u2.x + f2.x, 0.0f) +
                w2b.y * fmaxf(u2.y + f2.y, 0.0f) +
                w2b.z * fmaxf(u3.x + f3.x, 0.0f) +
                w2b.w * fmaxf(u3.y + f3.y, 0.0f);

            s += __shfl_xor(s, 8, 16);
            s += __shfl_xor(s, 4, 16);
            s += __shfl_xor(s, 2, 16);
            s += __shfl_xor(s, 1, 16);

            const int e = e0 + i * nG;
            if (lane == 0 && e < E) {
                float x = s + bias;
                out[e] = 1.0f / (1.0f + __expf(-x));
            }
        }
    }
}

extern "C" void kernel_launch(void* const* d_in, const int* in_sizes, int n_in,
                              void* d_out, int out_size, void* d_ws, size_t ws_size,
                              hipStream_t stream) {
    const float* z_user = (const float*)d_in[0];
    const float* z_food = (const float*)d_in[1];
    const int*   row    = (const int*)d_in[2];
    const int*   col    = (const int*)d_in[3];
    const float* W1     = (const float*)d_in[4];
    const float* b1     = (const float*)d_in[5];
    const float* gamma  = (const float*)d_in[6];
    const float* beta   = (const float*)d_in[7];
    const float* rm     = (const float*)d_in[8];
    const float* rv     = (const float*)d_in[9];
    const float* W2     = (const float*)d_in[10];
    const float* b2     = (const float*)d_in[11];
    float* out = (float*)d_out;

    const int n_users = in_sizes[0] / H;
    const int n_foods = in_sizes[1] / H;
    const int E       = in_sizes[2];

    // workspace layout
    unsigned short* U      = (unsigned short*)d_ws;        // n_users*128 bf16
    unsigned short* F      = U + (size_t)n_users * H;      // n_foods*128 bf16
    unsigned short* Wswz_u = F + (size_t)n_foods * H;      // 128*128 bf16, frag order
    unsigned short* Wswz_f = Wswz_u + H * H;               // 128*128 bf16, frag order
    float*          d_usr  = (float*)(Wswz_f + H * H);     // 128 f32
    int*            binCursor = (int*)(d_usr + H);         // 64 ints
    int*            bpk    = binCursor + NBMAX;            // nb*CAP packed (row,coff)

    const int nb = (n_foods + (1 << BIN_SHIFT) - 1) >> BIN_SHIFT;
    int*   slotOf = bpk + (size_t)nb * CAP;                // E ints
    float* res    = (float*)(slotOf + (size_t)E);          // nb*CAP f32
    const size_t need = (size_t)((char*)(res + (size_t)nb * CAP) - (char*)d_ws);
    const bool binned = (nb >= 1 && nb <= NBMAX &&
                         n_users <= (1 << (31 - BIN_SHIFT)) &&
                         ws_size >= need);

    prep_kernel<<<32, 64, 0, stream>>>(W1, b1, gamma, beta, rm, rv,
                                       Wswz_u, Wswz_f, d_usr,
                                       binCursor, binned ? 1 : 0);

    if (binned)
        bin_scatter<<<1024, 256, 0, stream>>>(row, col, E, binCursor, bpk, slotOf);

    // persistent: ~2 blocks/CU, 2:1 user:food split matches row ratio
    const int GU = 342, GB = 512;
    proj_mfma<<<GB, 256, 0, stream>>>(z_user, z_food, Wswz_u, Wswz_f, d_usr,
                                      U, F, n_users, n_foods, GU, GB);

    if (binned) {
        edge_binned<<<nb * (CAP / 64), 256, 0, stream>>>(U, F, bpk, binCursor,
                                                         W2, b2, res);
        unscatter<<<2048, 256, 0, stream>>>(res, slotOf, out, E);
    } else {
        edge_kernel<<<8192, 256, 0, stream>>>(U, F, row, col, W2, b2, out, E);
    }
}

// Round 3
// 225.544 us; speedup vs baseline: 1.0411x; 1.0111x over previous
//
#include <hip/hip_runtime.h>
#include <hip/hip_bf16.h>
#include <math.h>

#define H 128
#define EPS 1e-5f
#define INF_BIAS 0.1f

// ---- edge-binning parameters ----
// bin = col >> BIN_SHIFT : 1024 food rows/bin = 256 KB bf16 window (L2-resident)
#define BIN_SHIFT 10
#define CAP 24576          // slots per bin; E/nb ~ 20.4k expected, +29 sigma margin
#define NBMAX 64
#define BS_CHUNK 1024      // edges per bin_scatter block (LDS reorder buffer)

typedef __attribute__((ext_vector_type(8))) short bf16x8;
typedef __attribute__((ext_vector_type(4))) float f32x4;
typedef __attribute__((ext_vector_type(4))) unsigned int u32x4;

// ---- bf16 helpers (RNE) ----
__device__ inline unsigned short f2bf_rne(float f) {
    unsigned u = __float_as_uint(f);
    u += 0x7fffu + ((u >> 16) & 1u);
    return (unsigned short)(u >> 16);
}
__device__ inline float bf2f(unsigned short h) {
    return __uint_as_float(((unsigned)h) << 16);
}
__device__ inline unsigned pack2(float a, float b) {
    return (unsigned)f2bf_rne(a) | ((unsigned)f2bf_rne(b) << 16);
}
__device__ inline float2 unpack2(unsigned v) {
    float2 r;
    r.x = __uint_as_float(v << 16);
    r.y = __uint_as_float(v & 0xffff0000u);
    return r;
}

// ---------------------------------------------------------------------------
// prep: BN-prescaled bf16 W in MFMA A-fragment order (unchanged math) +
// zeroing of the 64 bin cursors (runs before bin_scatter in stream order).
// ---------------------------------------------------------------------------
__global__ void prep_kernel(
    const float* __restrict__ W1, const float* __restrict__ b1,
    const float* __restrict__ gamma, const float* __restrict__ beta,
    const float* __restrict__ rm, const float* __restrict__ rv,
    unsigned short* __restrict__ Wswz_u, unsigned short* __restrict__ Wswz_f,
    float* __restrict__ d_user, int* __restrict__ binCursor, int useBinned)
{
    const int f    = blockIdx.x;          // 0..31
    const int half = f >> 4, nt = (f >> 2) & 3, kt = f & 3;
    const int t    = threadIdx.x;         // 0..63
    const int c    = t & 15, q = t >> 4;

    if (useBinned && f == 0) binCursor[t] = 0;   // 64 cursors, one per thread

    const int j  = half * 64 + (c >> 2) * 16 + nt * 4 + (c & 3);
    const float a = gamma[j] * rsqrtf(rv[j] + EPS);
    const int k0 = kt * 32 + q * 8;

    unsigned short wu[8], wf[8];
    #pragma unroll
    for (int i = 0; i < 8; ++i) {
        wu[i] = f2bf_rne(a * W1[(size_t)j * (2 * H) + k0 + i]);
        wf[i] = f2bf_rne(a * W1[(size_t)j * (2 * H) + H + k0 + i]);
    }
    const size_t dst = (size_t)f * 512 + (size_t)t * 8;   // ushort units
    #pragma unroll
    for (int i = 0; i < 8; ++i) { Wswz_u[dst + i] = wu[i]; Wswz_f[dst + i] = wf[i]; }

    if (kt == 0 && q == 0) d_user[j] = a * (b1[j] - rm[j]) + beta[j];
}

// ---------------------------------------------------------------------------
// proj_mfma v8 (unchanged): persistent waves + register double-buffered Z
// prefetch. Bit-identical per-tile math to previous rounds.
// ---------------------------------------------------------------------------
__global__ __launch_bounds__(256, 2) void proj_mfma(
    const float* __restrict__ z_user, const float* __restrict__ z_food,
    const unsigned short* __restrict__ Wswz_u, const unsigned short* __restrict__ Wswz_f,
    const float* __restrict__ d_user,
    unsigned short* __restrict__ U, unsigned short* __restrict__ F,
    int n_users, int n_foods, int GU, int GB)
{
    const bool userMode = (blockIdx.x < (unsigned)GU);
    const float* Z;
    const unsigned short* Wsrc;
    unsigned short* Out;
    int n, blk0, nblk;
    if (userMode) { Z = z_user; Wsrc = Wswz_u; Out = U; n = n_users; blk0 = blockIdx.x;      nblk = GU; }
    else          { Z = z_food; Wsrc = Wswz_f; Out = F; n = n_foods; blk0 = blockIdx.x - GU; nblk = GB - GU; }
    const int tiles = n >> 4;               // n divisible by 16

    const int wave = threadIdx.x >> 6;
    const int lane = threadIdx.x & 63;
    const int c = lane & 15;                // row within tile
    const int q = lane >> 4;                // k-group / 16-col subgroup
    const int wg   = blk0 * 4 + wave;       // global wave id within mode
    const int half = wg & 1;                // 64-col half
    const int pair = wg >> 1;               // tile-pair id
    const int stride = nblk * 2;            // tile stride between iterations

    bf16x8 wf[4][4];
    #pragma unroll
    for (int nt = 0; nt < 4; ++nt)
        #pragma unroll
        for (int kt = 0; kt < 4; ++kt)
            wf[nt][kt] = *(const bf16x8*)(Wsrc + (size_t)(half * 16 + nt * 4 + kt) * 512 + lane * 8);

    f32x4 dvec[4];
    #pragma unroll
    for (int nt = 0; nt < 4; ++nt) {
        if (userMode) {
            float4 d = *(const float4*)(d_user + half * 64 + q * 16 + nt * 4);
            dvec[nt] = (f32x4){d.x, d.y, d.z, d.w};
        } else {
            dvec[nt] = (f32x4){0.f, 0.f, 0.f, 0.f};
        }
    }

    auto loadZ = [&](int t, float4 zb[8]) {
        const float* zrow = Z + (size_t)(min(t, tiles - 1) * 16 + c) * H;
        #pragma unroll
        for (int kt = 0; kt < 4; ++kt) {
            const int k0 = kt * 32 + q * 8;
            zb[2 * kt + 0] = ((const float4*)(zrow + k0))[0];
            zb[2 * kt + 1] = ((const float4*)(zrow + k0))[1];
        }
    };

    auto computeStore = [&](int t, const float4 zb[8]) {
        f32x4 acc[4];
        #pragma unroll
        for (int nt = 0; nt < 4; ++nt) acc[nt] = dvec[nt];

        #pragma unroll
        for (int kt = 0; kt < 4; ++kt) {
            float4 za = zb[2 * kt + 0];
            float4 zv = zb[2 * kt + 1];
            bf16x8 zhi, zlo;
            {
                float v[8] = {za.x, za.y, za.z, za.w, zv.x, zv.y, zv.z, zv.w};
                #pragma unroll
                for (int i = 0; i < 8; ++i) {
                    unsigned short hi = f2bf_rne(v[i]);
                    unsigned short lo = f2bf_rne(v[i] - bf2f(hi));
                    zhi[i] = (short)hi; zlo[i] = (short)lo;
                }
            }
            #pragma unroll
            for (int nt = 0; nt < 4; ++nt) {
                acc[nt] = __builtin_amdgcn_mfma_f32_16x16x32_bf16(wf[nt][kt], zhi, acc[nt], 0, 0, 0);
                acc[nt] = __builtin_amdgcn_mfma_f32_16x16x32_bf16(wf[nt][kt], zlo, acc[nt], 0, 0, 0);
            }
        }

        if (t < tiles) {
            const int r = t * 16 + c;
            unsigned short* obase = Out + (size_t)r * H + half * 64 + q * 16;
            uint4 p0, p1;
            p0.x = pack2(acc[0][0], acc[0][1]); p0.y = pack2(acc[0][2], acc[0][3]);
            p0.z = pack2(acc[1][0], acc[1][1]); p0.w = pack2(acc[1][2], acc[1][3]);
            p1.x = pack2(acc[2][0], acc[2][1]); p1.y = pack2(acc[2][2], acc[2][3]);
            p1.z = pack2(acc[3][0], acc[3][1]); p1.w = pack2(acc[3][2], acc[3][3]);
            *(uint4*)(obase)     = p0;
            *(uint4*)(obase + 8) = p1;
        }
    };

    int nIt = (tiles + stride - 1) / stride;
    nIt = (nIt + 1) & ~1;                   // even, for 2x unrolled pipeline

    float4 zb0[8], zb1[8];
    int t = pair;
    loadZ(t, zb0);
    for (int it = 0; it < nIt; it += 2) {
        loadZ(t + stride, zb1);
        computeStore(t, zb0);
        if (it + 2 < nIt) loadZ(t + 2 * stride, zb0);
        computeStore(t + stride, zb1);
        t += 2 * stride;
    }
}

// ---------------------------------------------------------------------------
// bin_scatter v3: block-local LDS counting-sort, then run-coalesced global
// stores. Eliminates the RFO penalty of 1M random 4B stores: within each
// per-bin run, consecutive threads write consecutive addresses -> the HW
// coalescer emits full-line stores. slotOf[e] remains coalesced in e.
// ---------------------------------------------------------------------------
__global__ __launch_bounds__(256) void bin_scatter(
    const int* __restrict__ row, const int* __restrict__ col, int E,
    int* __restrict__ binCursor,
    int* __restrict__ bpk, int* __restrict__ slotOf)
{
    __shared__ int h[NBMAX];      // histogram -> scatter cursor
    __shared__ int pfx[NBMAX];    // local exclusive prefix
    __shared__ int gb[NBMAX];     // global base slot for this block's run
    __shared__ int vbuf[BS_CHUNK];
    __shared__ int gposbuf[BS_CHUNK];

    const int t  = threadIdx.x;
    const int e0 = blockIdx.x * BS_CHUNK;
    const int e1 = min(E, e0 + BS_CHUNK);
    const int nE = e1 - e0;
    if (nE <= 0) return;

    if (t < NBMAX) h[t] = 0;
    __syncthreads();

    // phase 1: load my edges (<=4), LDS histogram
    int rr[4], bb[4], co[4];
    int myN = 0;
    for (int e = e0 + t; e < e1; e += 256) {
        const int c = col[e];
        rr[myN] = row[e];
        bb[myN] = c >> BIN_SHIFT;
        co[myN] = c & ((1 << BIN_SHIFT) - 1);
        atomicAdd(&h[bb[myN]], 1);
        ++myN;
    }
    __syncthreads();

    // phase 2 (wave 0 only): 64-wide exclusive scan + global reservation
    if (t < NBMAX) {
        const int cnt = h[t];
        int v = cnt;
        #pragma unroll
        for (int ofs = 1; ofs < 64; ofs <<= 1) {
            int u = __shfl_up(v, ofs, 64);
            if (t >= ofs) v += u;
        }
        pfx[t] = v - cnt;                          // exclusive prefix
        const int old = cnt ? atomicAdd(&binCursor[t], cnt) : 0;
        gb[t] = t * CAP + old;
        h[t]  = v - cnt;                           // reuse as scatter cursor
    }
    __syncthreads();

    // phase 3: LDS scatter (cheap), record global positions; slotOf coalesced
    #pragma unroll 4
    for (int i = 0; i < myN; ++i) {
        const int b    = bb[i];
        const int lpos = atomicAdd(&h[b], 1);
        int gp = gb[b] + (lpos - pfx[b]);
        gp = min(gp, (b + 1) * CAP - 1);           // overflow clamp (stat. impossible)
        vbuf[lpos]    = (rr[i] << BIN_SHIFT) | co[i];
        gposbuf[lpos] = gp;
        slotOf[e0 + t + i * 256] = gp;
    }
    __syncthreads();

    // phase 4: run-coalesced global stores (consecutive i -> consecutive gpos
    // within each bin run)
    for (int i = t; i < nE; i += 256)
        bpk[gposbuf[i]] = vbuf[i];
}

// ---------------------------------------------------------------------------
// edge_binned v3: XCD-chunked virtual block order. blockIdx -> XCD is
// round-robin on MI355X, so vb = (bid&7)*(G/8) + bid/8 gives each XCD a
// CONTIGUOUS slot (=bin) range: each 256 KB F-window is fetched into exactly
// one XCD's L2, once, instead of 8x. U gathers stay non-temporal.
// Per-edge arithmetic bit-identical to previous rounds.
// ---------------------------------------------------------------------------
__global__ __launch_bounds__(256) void edge_binned(
    const unsigned short* __restrict__ U, const unsigned short* __restrict__ F,
    const int* __restrict__ bpk, const int* __restrict__ binCursor,
    const float* __restrict__ W2, const float* __restrict__ b2,
    float* __restrict__ res)
{
    const int cpx   = gridDim.x >> 3;        // grid is a multiple of 8
    const int vb    = (blockIdx.x & 7) * cpx + (blockIdx.x >> 3);
    const int lane  = threadIdx.x & 15;
    const int g     = (vb * 256 + (int)threadIdx.x) >> 4;
    const int slot0 = g * 4;                 // 4 consecutive slots, same bin (CAP%4==0)
    const int bin   = slot0 / CAP;
    const int cnt   = min(binCursor[bin], CAP);
    const int idx0  = slot0 - bin * CAP;
    if (idx0 >= cnt) return;                 // whole group past this bin's fill

    const float4 w2a = ((const float4*)W2)[2 * lane];
    const float4 w2b = ((const float4*)W2)[2 * lane + 1];
    const float bias = b2[0] + INF_BIAS;
    const int   fbase = bin << BIN_SHIFT;

    int iu[4], ifo[4];
    #pragma unroll
    for (int i = 0; i < 4; ++i) {
        const int s = (idx0 + i < cnt) ? (slot0 + i) : slot0;
        const int v = bpk[s];
        iu[i]  = v >> BIN_SHIFT;
        ifo[i] = fbase + (v & ((1 << BIN_SHIFT) - 1));
    }
    u32x4 uv[4];
    uint4 fv[4];
    #pragma unroll
    for (int i = 0; i < 4; ++i) {
        uv[i] = __builtin_nontemporal_load(((const u32x4*)(U + (size_t)iu[i] * H)) + lane);
        fv[i] = ((const uint4*)(F + (size_t)ifo[i] * H))[lane];
    }
    float r[4];
    #pragma unroll
    for (int i = 0; i < 4; ++i) {
        float2 u0 = unpack2(uv[i][0]), f0 = unpack2(fv[i].x);
        float2 u1 = unpack2(uv[i][1]), f1 = unpack2(fv[i].y);
        float2 u2 = unpack2(uv[i][2]), f2 = unpack2(fv[i].z);
        float2 u3 = unpack2(uv[i][3]), f3 = unpack2(fv[i].w);

        float s =
            w2a.x * fmaxf(u0.x + f0.x, 0.0f) +
            w2a.y * fmaxf(u0.y + f0.y, 0.0f) +
            w2a.z * fmaxf(u1.x + f1.x, 0.0f) +
            w2a.w * fmaxf(u1.y + f1.y, 0.0f) +
            w2b.x * fmaxf(u2.x + f2.x, 0.0f) +
            w2b.y * fmaxf(u2.y + f2.y, 0.0f) +
            w2b.z * fmaxf(u3.x + f3.x, 0.0f) +
            w2b.w * fmaxf(u3.y + f3.y, 0.0f);

        s += __shfl_xor(s, 8, 16);
        s += __shfl_xor(s, 4, 16);
        s += __shfl_xor(s, 2, 16);
        s += __shfl_xor(s, 1, 16);

        const float x = s + bias;
        r[i] = 1.0f / (1.0f + __expf(-x));
    }
    if (lane == 0) {                         // contiguous 16B per group, 64B per wave
        float4 o; o.x = r[0]; o.y = r[1]; o.z = r[2]; o.w = r[3];
        *(float4*)(res + slot0) = o;
    }
}

// ---------------------------------------------------------------------------
// unscatter: out[e] = res[slotOf[e]]. Coalesced int4/float4 in e; the res
// gather is confined to the 4.8 MB res array (cache-resident).
// ---------------------------------------------------------------------------
__global__ __launch_bounds__(256) void unscatter(
    const float* __restrict__ res, const int* __restrict__ slotOf,
    float* __restrict__ out, int E)
{
    const int tid = blockIdx.x * blockDim.x + threadIdx.x;
    const int nT  = gridDim.x * blockDim.x;
    const int n4  = E >> 2;
    for (int i = tid; i < n4; i += nT) {
        int4 s = ((const int4*)slotOf)[i];
        float4 o;
        o.x = res[s.x]; o.y = res[s.y]; o.z = res[s.z]; o.w = res[s.w];
        ((float4*)out)[i] = o;
    }
    for (int e = (n4 << 2) + tid; e < E; e += nT)
        out[e] = res[slotOf[e]];
}

// ---------------------------------------------------------------------------
// edge kernel v2 (fallback path if workspace too small): unchanged.
// ---------------------------------------------------------------------------
#define EUN 4
__global__ __launch_bounds__(256) void edge_kernel(
    const unsigned short* __restrict__ U, const unsigned short* __restrict__ F,
    const int* __restrict__ row, const int* __restrict__ col,
    const float* __restrict__ W2, const float* __restrict__ b2,
    float* __restrict__ out, int E)
{
    const int lane = threadIdx.x & 15;
    const int g  = (blockIdx.x * blockDim.x + threadIdx.x) >> 4;
    const int nG = (gridDim.x * blockDim.x) >> 4;

    const float4 w2a = ((const float4*)W2)[2 * lane];
    const float4 w2b = ((const float4*)W2)[2 * lane + 1];
    const float bias = b2[0] + INF_BIAS;

    for (int e0 = g; e0 < E; e0 += EUN * nG) {
        int iu[EUN], ifo[EUN];
        #pragma unroll
        for (int i = 0; i < EUN; ++i) {
            int e  = e0 + i * nG;
            int ec = (e < E) ? e : e0;
            iu[i]  = row[ec];
            ifo[i] = col[ec];
        }
        uint4 uv[EUN], fv[EUN];
        #pragma unroll
        for (int i = 0; i < EUN; ++i) {
            uv[i] = ((const uint4*)(U + (size_t)iu[i]  * H))[lane];
            fv[i] = ((const uint4*)(F + (size_t)ifo[i] * H))[lane];
        }
        #pragma unroll
        for (int i = 0; i < EUN; ++i) {
            float2 u0 = unpack2(uv[i].x), f0 = unpack2(fv[i].x);
            float2 u1 = unpack2(uv[i].y), f1 = unpack2(fv[i].y);
            float2 u2 = unpack2(uv[i].z), f2 = unpack2(fv[i].z);
            float2 u3 = unpack2(uv[i].w), f3 = unpack2(fv[i].w);

            float s =
                w2a.x * fmaxf(u0.x + f0.x, 0.0f) +
                w2a.y * fmaxf(u0.y + f0.y, 0.0f) +
                w2a.z * fmaxf(u1.x + f1.x, 0.0f) +
                w2a.w * fmaxf(u1.y + f1.y, 0.0f) +
                w2b.x * fmaxf(u2.x + f2.x, 0.0f) +
                w2b.y * fmaxf(u2.y + f2.y, 0.0f) +
                w2b.z * fmaxf(u3.x + f3.x, 0.0f) +
                w2b.w * fmaxf(u3.y + f3.y, 0.0f);

            s += __shfl_xor(s, 8, 16);
            s += __shfl_xor(s, 4, 16);
            s += __shfl_xor(s, 2, 16);
            s += __shfl_xor(s, 1, 16);

            const int e = e0 + i * nG;
            if (lane == 0 && e < E) {
                float x = s + bias;
                out[e] = 1.0f / (1.0f + __expf(-x));
            }
        }
    }
}

extern "C" void kernel_launch(void* const* d_in, const int* in_sizes, int n_in,
                              void* d_out, int out_size, void* d_ws, size_t ws_size,
                              hipStream_t stream) {
    const float* z_user = (const float*)d_in[0];
    const float* z_food = (const float*)d_in[1];
    const int*   row    = (const int*)d_in[2];
    const int*   col    = (const int*)d_in[3];
    const float* W1     = (const float*)d_in[4];
    const float* b1     = (const float*)d_in[5];
    const float* gamma  = (const float*)d_in[6];
    const float* beta   = (const float*)d_in[7];
    const float* rm     = (const float*)d_in[8];
    const float* rv     = (const float*)d_in[9];
    const float* W2     = (const float*)d_in[10];
    const float* b2     = (const float*)d_in[11];
    float* out = (float*)d_out;

    const int n_users = in_sizes[0] / H;
    const int n_foods = in_sizes[1] / H;
    const int E       = in_sizes[2];

    // workspace layout
    unsigned short* U      = (unsigned short*)d_ws;        // n_users*128 bf16
    unsigned short* F      = U + (size_t)n_users * H;      // n_foods*128 bf16
    unsigned short* Wswz_u = F + (size_t)n_foods * H;      // 128*128 bf16, frag order
    unsigned short* Wswz_f = Wswz_u + H * H;               // 128*128 bf16, frag order
    float*          d_usr  = (float*)(Wswz_f + H * H);     // 128 f32
    int*            binCursor = (int*)(d_usr + H);         // 64 ints
    int*            bpk    = binCursor + NBMAX;            // nb*CAP packed (row,coff)

    const int nb = (n_foods + (1 << BIN_SHIFT) - 1) >> BIN_SHIFT;
    int*   slotOf = bpk + (size_t)nb * CAP;                // E ints
    float* res    = (float*)(slotOf + (size_t)E);          // nb*CAP f32
    const size_t need = (size_t)((char*)(res + (size_t)nb * CAP) - (char*)d_ws);
    const bool binned = (nb >= 1 && nb <= NBMAX &&
                         n_users <= (1 << (31 - BIN_SHIFT)) &&
                         ws_size >= need);

    prep_kernel<<<32, 64, 0, stream>>>(W1, b1, gamma, beta, rm, rv,
                                       Wswz_u, Wswz_f, d_usr,
                                       binCursor, binned ? 1 : 0);

    if (binned)
        bin_scatter<<<(E + BS_CHUNK - 1) / BS_CHUNK, 256, 0, stream>>>(
            row, col, E, binCursor, bpk, slotOf);

    // persistent: ~2 blocks/CU, 2:1 user:food split matches row ratio
    const int GU = 342, GB = 512;
    proj_mfma<<<GB, 256, 0, stream>>>(z_user, z_food, Wswz_u, Wswz_f, d_usr,
                                      U, F, n_users, n_foods, GU, GB);

    if (binned) {
        // grid = nb*384, always a multiple of 8 (384 = CAP/64)
        edge_binned<<<nb * (CAP / 64), 256, 0, stream>>>(U, F, bpk, binCursor,
                                                         W2, b2, res);
        unscatter<<<2048, 256, 0, stream>>>(res, slotOf, out, E);
    } else {
        edge_kernel<<<8192, 256, 0, stream>>>(U, F, row, col, W2, b2, out, E);
    }
}

// Round 4
// 206.363 us; speedup vs baseline: 1.1379x; 1.0929x over previous
//
#include <hip/hip_runtime.h>
#include <hip/hip_bf16.h>
#include <math.h>

#define H 128
#define EPS 1e-5f
#define INF_BIAS 0.1f

typedef __attribute__((ext_vector_type(8))) short bf16x8;
typedef __attribute__((ext_vector_type(4))) float f32x4;

// ---- bf16 helpers (RNE) ----
__device__ inline unsigned short f2bf_rne(float f) {
    unsigned u = __float_as_uint(f);
    u += 0x7fffu + ((u >> 16) & 1u);
    return (unsigned short)(u >> 16);
}
__device__ inline float bf2f(unsigned short h) {
    return __uint_as_float(((unsigned)h) << 16);
}
__device__ inline unsigned pack2(float a, float b) {
    return (unsigned)f2bf_rne(a) | ((unsigned)f2bf_rne(b) << 16);
}
__device__ inline float2 unpack2(unsigned v) {
    float2 r;
    r.x = __uint_as_float(v << 16);
    r.y = __uint_as_float(v & 0xffff0000u);
    return r;
}

// ---------------------------------------------------------------------------
// prep: BN-prescaled bf16 W in MFMA A-fragment order with PERMUTED j->m
// mapping (epilogue contiguity). Unchanged math from prior rounds.
// ---------------------------------------------------------------------------
__global__ void prep_kernel(
    const float* __restrict__ W1, const float* __restrict__ b1,
    const float* __restrict__ gamma, const float* __restrict__ beta,
    const float* __restrict__ rm, const float* __restrict__ rv,
    unsigned short* __restrict__ Wswz_u, unsigned short* __restrict__ Wswz_f,
    float* __restrict__ d_user)
{
    const int f    = blockIdx.x;          // 0..31
    const int half = f >> 4, nt = (f >> 2) & 3, kt = f & 3;
    const int t    = threadIdx.x;         // 0..63
    const int c    = t & 15, q = t >> 4;

    const int j  = half * 64 + (c >> 2) * 16 + nt * 4 + (c & 3);
    const float a = gamma[j] * rsqrtf(rv[j] + EPS);
    const int k0 = kt * 32 + q * 8;

    unsigned short wu[8], wf[8];
    #pragma unroll
    for (int i = 0; i < 8; ++i) {
        wu[i] = f2bf_rne(a * W1[(size_t)j * (2 * H) + k0 + i]);
        wf[i] = f2bf_rne(a * W1[(size_t)j * (2 * H) + H + k0 + i]);
    }
    const size_t dst = (size_t)f * 512 + (size_t)t * 8;   // ushort units
    #pragma unroll
    for (int i = 0; i < 8; ++i) { Wswz_u[dst + i] = wu[i]; Wswz_f[dst + i] = wf[i]; }

    if (kt == 0 && q == 0) d_user[j] = a * (b1[j] - rm[j]) + beta[j];
}

// ---------------------------------------------------------------------------
// proj_mfma v8 (unchanged): persistent waves + register double-buffered Z
// prefetch. Bit-identical per-tile math to previous rounds.
// ---------------------------------------------------------------------------
__global__ __launch_bounds__(256, 2) void proj_mfma(
    const float* __restrict__ z_user, const float* __restrict__ z_food,
    const unsigned short* __restrict__ Wswz_u, const unsigned short* __restrict__ Wswz_f,
    const float* __restrict__ d_user,
    unsigned short* __restrict__ U, unsigned short* __restrict__ F,
    int n_users, int n_foods, int GU, int GB)
{
    const bool userMode = (blockIdx.x < (unsigned)GU);
    const float* Z;
    const unsigned short* Wsrc;
    unsigned short* Out;
    int n, blk0, nblk;
    if (userMode) { Z = z_user; Wsrc = Wswz_u; Out = U; n = n_users; blk0 = blockIdx.x;      nblk = GU; }
    else          { Z = z_food; Wsrc = Wswz_f; Out = F; n = n_foods; blk0 = blockIdx.x - GU; nblk = GB - GU; }
    const int tiles = n >> 4;               // n divisible by 16

    const int wave = threadIdx.x >> 6;
    const int lane = threadIdx.x & 63;
    const int c = lane & 15;                // row within tile
    const int q = lane >> 4;                // k-group / 16-col subgroup
    const int wg   = blk0 * 4 + wave;       // global wave id within mode
    const int half = wg & 1;                // 64-col half
    const int pair = wg >> 1;               // tile-pair id
    const int stride = nblk * 2;            // tile stride between iterations

    bf16x8 wf[4][4];
    #pragma unroll
    for (int nt = 0; nt < 4; ++nt)
        #pragma unroll
        for (int kt = 0; kt < 4; ++kt)
            wf[nt][kt] = *(const bf16x8*)(Wsrc + (size_t)(half * 16 + nt * 4 + kt) * 512 + lane * 8);

    f32x4 dvec[4];
    #pragma unroll
    for (int nt = 0; nt < 4; ++nt) {
        if (userMode) {
            float4 d = *(const float4*)(d_user + half * 64 + q * 16 + nt * 4);
            dvec[nt] = (f32x4){d.x, d.y, d.z, d.w};
        } else {
            dvec[nt] = (f32x4){0.f, 0.f, 0.f, 0.f};
        }
    }

    auto loadZ = [&](int t, float4 zb[8]) {
        const float* zrow = Z + (size_t)(min(t, tiles - 1) * 16 + c) * H;
        #pragma unroll
        for (int kt = 0; kt < 4; ++kt) {
            const int k0 = kt * 32 + q * 8;
            zb[2 * kt + 0] = ((const float4*)(zrow + k0))[0];
            zb[2 * kt + 1] = ((const float4*)(zrow + k0))[1];
        }
    };

    auto computeStore = [&](int t, const float4 zb[8]) {
        f32x4 acc[4];
        #pragma unroll
        for (int nt = 0; nt < 4; ++nt) acc[nt] = dvec[nt];

        #pragma unroll
        for (int kt = 0; kt < 4; ++kt) {
            float4 za = zb[2 * kt + 0];
            float4 zv = zb[2 * kt + 1];
            bf16x8 zhi, zlo;
            {
                float v[8] = {za.x, za.y, za.z, za.w, zv.x, zv.y, zv.z, zv.w};
                #pragma unroll
                for (int i = 0; i < 8; ++i) {
                    unsigned short hi = f2bf_rne(v[i]);
                    unsigned short lo = f2bf_rne(v[i] - bf2f(hi));
                    zhi[i] = (short)hi; zlo[i] = (short)lo;
                }
            }
            #pragma unroll
            for (int nt = 0; nt < 4; ++nt) {
                acc[nt] = __builtin_amdgcn_mfma_f32_16x16x32_bf16(wf[nt][kt], zhi, acc[nt], 0, 0, 0);
                acc[nt] = __builtin_amdgcn_mfma_f32_16x16x32_bf16(wf[nt][kt], zlo, acc[nt], 0, 0, 0);
            }
        }

        if (t < tiles) {
            const int r = t * 16 + c;
            unsigned short* obase = Out + (size_t)r * H + half * 64 + q * 16;
            uint4 p0, p1;
            p0.x = pack2(acc[0][0], acc[0][1]); p0.y = pack2(acc[0][2], acc[0][3]);
            p0.z = pack2(acc[1][0], acc[1][1]); p0.w = pack2(acc[1][2], acc[1][3]);
            p1.x = pack2(acc[2][0], acc[2][1]); p1.y = pack2(acc[2][2], acc[2][3]);
            p1.z = pack2(acc[3][0], acc[3][1]); p1.w = pack2(acc[3][2], acc[3][3]);
            *(uint4*)(obase)     = p0;
            *(uint4*)(obase + 8) = p1;
        }
    };

    int nIt = (tiles + stride - 1) / stride;
    nIt = (nIt + 1) & ~1;                   // even, for 2x unrolled pipeline

    float4 zb0[8], zb1[8];
    int t = pair;
    loadZ(t, zb0);
    for (int it = 0; it < nIt; it += 2) {
        loadZ(t + stride, zb1);
        computeStore(t, zb0);
        if (it + 2 < nIt) loadZ(t + 2 * stride, zb0);
        computeStore(t + stride, zb1);
        t += 2 * stride;
    }
}

// ---------------------------------------------------------------------------
// edge kernel v3: 8-deep gather pipeline. Rounds 0-3 showed the gather is
// LATENCY-bound (no pipe >60%): binned variant at 2.1 TB/s FETCH / 54% VALU,
// plain variant at ~7.4 TB/s effective L3 with only 8 loads in flight.
// EUN=8 puts 16 index loads then 16 uint4 gathers in flight per thread
// before any use. __launch_bounds__(256,4) caps VGPR at 128 (no spill,
// ~16 waves/CU) so total outstanding-loads/CU roughly doubles.
// Per-edge arithmetic bit-identical to all prior rounds.
// ---------------------------------------------------------------------------
#define EUN 8
__global__ __launch_bounds__(256, 4) void edge_kernel(
    const unsigned short* __restrict__ U, const unsigned short* __restrict__ F,
    const int* __restrict__ row, const int* __restrict__ col,
    const float* __restrict__ W2, const float* __restrict__ b2,
    float* __restrict__ out, int E)
{
    const int lane = threadIdx.x & 15;
    const int g  = (blockIdx.x * blockDim.x + threadIdx.x) >> 4;
    const int nG = (gridDim.x * blockDim.x) >> 4;

    const float4 w2a = ((const float4*)W2)[2 * lane];
    const float4 w2b = ((const float4*)W2)[2 * lane + 1];
    const float bias = b2[0] + INF_BIAS;

    for (int e0 = g; e0 < E; e0 += EUN * nG) {
        int iu[EUN], ifo[EUN];
        #pragma unroll
        for (int i = 0; i < EUN; ++i) {
            int e  = e0 + i * nG;
            int ec = (e < E) ? e : e0;
            iu[i]  = row[ec];
            ifo[i] = col[ec];
        }
        uint4 uv[EUN], fv[EUN];
        #pragma unroll
        for (int i = 0; i < EUN; ++i) {
            uv[i] = ((const uint4*)(U + (size_t)iu[i]  * H))[lane];
            fv[i] = ((const uint4*)(F + (size_t)ifo[i] * H))[lane];
        }
        #pragma unroll
        for (int i = 0; i < EUN; ++i) {
            float2 u0 = unpack2(uv[i].x), f0 = unpack2(fv[i].x);
            float2 u1 = unpack2(uv[i].y), f1 = unpack2(fv[i].y);
            float2 u2 = unpack2(uv[i].z), f2 = unpack2(fv[i].z);
            float2 u3 = unpack2(uv[i].w), f3 = unpack2(fv[i].w);

            float s =
                w2a.x * fmaxf(u0.x + f0.x, 0.0f) +
                w2a.y * fmaxf(u0.y + f0.y, 0.0f) +
                w2a.z * fmaxf(u1.x + f1.x, 0.0f) +
                w2a.w * fmaxf(u1.y + f1.y, 0.0f) +
                w2b.x * fmaxf(u2.x + f2.x, 0.0f) +
                w2b.y * fmaxf(u2.y + f2.y, 0.0f) +
                w2b.z * fmaxf(u3.x + f3.x, 0.0f) +
                w2b.w * fmaxf(u3.y + f3.y, 0.0f);

            s += __shfl_xor(s, 8, 16);
            s += __shfl_xor(s, 4, 16);
            s += __shfl_xor(s, 2, 16);
            s += __shfl_xor(s, 1, 16);

            const int e = e0 + i * nG;
            if (lane == 0 && e < E) {
                float x = s + bias;
                out[e] = 1.0f / (1.0f + __expf(-x));
            }
        }
    }
}

extern "C" void kernel_launch(void* const* d_in, const int* in_sizes, int n_in,
                              void* d_out, int out_size, void* d_ws, size_t ws_size,
                              hipStream_t stream) {
    const float* z_user = (const float*)d_in[0];
    const float* z_food = (const float*)d_in[1];
    const int*   row    = (const int*)d_in[2];
    const int*   col    = (const int*)d_in[3];
    const float* W1     = (const float*)d_in[4];
    const float* b1     = (const float*)d_in[5];
    const float* gamma  = (const float*)d_in[6];
    const float* beta   = (const float*)d_in[7];
    const float* rm     = (const float*)d_in[8];
    const float* rv     = (const float*)d_in[9];
    const float* W2     = (const float*)d_in[10];
    const float* b2     = (const float*)d_in[11];
    float* out = (float*)d_out;

    const int n_users = in_sizes[0] / H;
    const int n_foods = in_sizes[1] / H;
    const int E       = in_sizes[2];

    // workspace layout
    unsigned short* U      = (unsigned short*)d_ws;        // n_users*128 bf16
    unsigned short* F      = U + (size_t)n_users * H;      // n_foods*128 bf16
    unsigned short* Wswz_u = F + (size_t)n_foods * H;      // 128*128 bf16, frag order
    unsigned short* Wswz_f = Wswz_u + H * H;               // 128*128 bf16, frag order
    float*          d_usr  = (float*)(Wswz_f + H * H);     // 128 f32

    prep_kernel<<<32, 64, 0, stream>>>(W1, b1, gamma, beta, rm, rv,
                                       Wswz_u, Wswz_f, d_usr);

    // persistent: ~2 blocks/CU, 2:1 user:food split matches row ratio
    const int GU = 342, GB = 512;
    proj_mfma<<<GB, 256, 0, stream>>>(z_user, z_food, Wswz_u, Wswz_f, d_usr,
                                      U, F, n_users, n_foods, GU, GB);

    edge_kernel<<<8192, 256, 0, stream>>>(U, F, row, col, W2, b2, out, E);
}